// Round 1
// baseline (476.937 us; speedup 1.0000x reference)
//
#include <hip/hip_runtime.h>

// SoftReordering: B=16, S=1024, E=1024, W=7 (fp32 in/out)
// out[b,t,e] = tanh( sum_w sigmoid(logit[b,t,w]) * win[b,t,w,e] )
// logit[b,t,v] = sum_{w,e} win[b,t,w,e] * weight[t, v, w*E+e] + bias[t,v]
// win[b,t,w,e] = x[b, t+w-3, e]  (0 if out of range)

#define Bq 16
#define Sq 1024
#define Eq 1024
#define Wq 7
#define HWq 3

__global__ __launch_bounds__(256, 4) void soft_reorder_kernel(
    const float* __restrict__ x,      // [B,S,E]
    const float* __restrict__ weight, // [S,W,W*E]
    const float* __restrict__ bias,   // [S,W]
    float* __restrict__ out)          // [B,S,E]
{
    const int bid = blockIdx.x;
    // XCD swizzle: block i -> XCD i%8; keep contiguous t ranges on one XCD
    const int t = (bid & 7) * (Sq / 8) + (bid >> 3);
    const int tid = threadIdx.x;
    const int b = tid >> 4;   // 0..15
    const int j = tid & 15;   // 0..15

    __shared__ float gates[Bq][Wq + 1];

    const float* wt = weight + (size_t)t * (Wq * Wq * Eq);

    float4 acc[Wq];
#pragma unroll
    for (int v = 0; v < Wq; ++v) acc[v] = make_float4(0.f, 0.f, 0.f, 0.f);

    // ---- Phase 1: logits ----
    // thread (b, j): partial dot over e-chunks k = ee + j*4, strided 64
#pragma unroll
    for (int w = 0; w < Wq; ++w) {
        const int row = t + w - HWq;
        if ((unsigned)row < (unsigned)Sq) {
            const float* xr = x + ((size_t)b * Sq + row) * Eq;
            const float* wr = wt + w * Eq;
            for (int ee = j * 4; ee < Eq; ee += 64) {
                const float4 xv = *(const float4*)(xr + ee);
#pragma unroll
                for (int v = 0; v < Wq; ++v) {
                    const float4 wv = *(const float4*)(wr + (size_t)v * (Wq * Eq) + ee);
                    acc[v].x += xv.x * wv.x;
                    acc[v].y += xv.y * wv.y;
                    acc[v].z += xv.z * wv.z;
                    acc[v].w += xv.w * wv.w;
                }
            }
        }
    }

    // reduce over the 16 j-lanes (they are contiguous lanes within the wave)
#pragma unroll
    for (int v = 0; v < Wq; ++v) {
        float s = acc[v].x + acc[v].y + acc[v].z + acc[v].w;
        s += __shfl_xor(s, 1, 16);
        s += __shfl_xor(s, 2, 16);
        s += __shfl_xor(s, 4, 16);
        s += __shfl_xor(s, 8, 16);
        if (j == 0) {
            const float logit = s + bias[t * Wq + v];
            gates[b][v] = 1.0f / (1.0f + __expf(-logit));
        }
    }
    __syncthreads();

    // ---- Phase 2: gated sum + tanh ----
    // each thread handles one float4 (e = tid*4) for every batch
    const int e = tid * 4;
    for (int bb = 0; bb < Bq; ++bb) {
        float g[Wq];
#pragma unroll
        for (int w = 0; w < Wq; ++w) g[w] = gates[bb][w];

        float4 a = make_float4(0.f, 0.f, 0.f, 0.f);
#pragma unroll
        for (int w = 0; w < Wq; ++w) {
            const int row = t + w - HWq;
            if ((unsigned)row < (unsigned)Sq) {
                const float4 xv = *(const float4*)(x + ((size_t)bb * Sq + row) * Eq + e);
                a.x += g[w] * xv.x;
                a.y += g[w] * xv.y;
                a.z += g[w] * xv.z;
                a.w += g[w] * xv.w;
            }
        }
        float4 o;
        o.x = 1.0f - 2.0f / (1.0f + __expf(2.0f * a.x));
        o.y = 1.0f - 2.0f / (1.0f + __expf(2.0f * a.y));
        o.z = 1.0f - 2.0f / (1.0f + __expf(2.0f * a.z));
        o.w = 1.0f - 2.0f / (1.0f + __expf(2.0f * a.w));
        *(float4*)(out + ((size_t)bb * Sq + t) * Eq + e) = o;
    }
}

extern "C" void kernel_launch(void* const* d_in, const int* in_sizes, int n_in,
                              void* d_out, int out_size, void* d_ws, size_t ws_size,
                              hipStream_t stream) {
    const float* x = (const float*)d_in[0];      // [16,1024,1024]
    const float* weight = (const float*)d_in[1]; // [1024,7,7168]
    const float* bias = (const float*)d_in[2];   // [1024,7]
    float* out = (float*)d_out;                  // [16,1024,1024]

    soft_reorder_kernel<<<Sq, 256, 0, stream>>>(x, weight, bias, out);
}